// Round 17
// baseline (137.025 us; speedup 1.0000x reference)
//
#include <hip/hip_runtime.h>
#include <hip/hip_bf16.h>

#define NT 21
#define NC 1000
#define NCP 1024
#define OD 32
#define CD 344
#define NEG 0.01f

#define RPB 2048            // rows per block (fwd_lds)
#define THR 512             // threads per block (fwd_lds)
#define SLICE 32768         // one (half,table) P slice: 1024 cats x 16 bf16
#define NS 42               // 2 halves x 21 tables

typedef float f32x4 __attribute__((ext_vector_type(4)));
typedef unsigned int u32x2 __attribute__((ext_vector_type(2)));

__device__ __forceinline__ unsigned short f32_to_bf16_rne(float f) {
    unsigned int u = __float_as_uint(f);
    unsigned int r = u + 0x7FFFu + ((u >> 16) & 1u);
    return (unsigned short)(r >> 16);
}
__device__ __forceinline__ float lrelu(float v) { return v >= 0.f ? v : NEG * v; }

// ---------------- new path: P2 sliced for LDS staging ----------------
// P2 element (s, h8, c, jj) at u16 index s*16384 + h8*8192 + c*8 + jj.
// value = dot(tables[t,c,:], W[h*16+h8*8+jj, 16t:16t+16)),  s = h*21 + t.
// Split-half layout (jj 0..7 at c*16, jj 8..15 at +16384) gives ds_read_b128
// start-banks 8 classes instead of 4 -> lower LDS conflict.
__global__ void build_P2(const float* __restrict__ tables,
                         const float* __restrict__ W,
                         unsigned short* __restrict__ P2) {
    int idx = blockIdx.x * 256 + threadIdx.x;
    if (idx >= NS * 16384) return;
    int jj = idx & 7;
    int c  = (idx >> 3) & (NCP - 1);
    int h8 = (idx >> 13) & 1;
    int s  = idx >> 14;
    int h = s / NT, t = s - h * NT;
    float v = 0.f;
    if (c < NC) {
        const float* tr = tables + (size_t)(t * NC + c) * 16;
        const float* wr = W + (size_t)(h * 16 + h8 * 8 + jj) * CD + t * 16;
        #pragma unroll
        for (int k = 0; k < 16; ++k) v = fmaf(tr[k], wr[k], v);
    }
    P2[idx] = f32_to_bf16_rne(v);
}

#define UNP8(ACC, I, BASE, V)                                         \
    ACC[I][BASE + 0] += __uint_as_float(V.x << 16);                   \
    ACC[I][BASE + 1] += __uint_as_float(V.x & 0xFFFF0000u);           \
    ACC[I][BASE + 2] += __uint_as_float(V.y << 16);                   \
    ACC[I][BASE + 3] += __uint_as_float(V.y & 0xFFFF0000u);           \
    ACC[I][BASE + 4] += __uint_as_float(V.z << 16);                   \
    ACC[I][BASE + 5] += __uint_as_float(V.z & 0xFFFF0000u);           \
    ACC[I][BASE + 6] += __uint_as_float(V.w << 16);                   \
    ACC[I][BASE + 7] += __uint_as_float(V.w & 0xFFFF0000u);

// one stage: ds_write staged regs -> barrier -> prefetch next slice -> gather
#define STAGE(S, T, ACC)                                                       \
    {                                                                          \
        uint4* dst = (uint4*)(s_P + ((S) & 1) * SLICE);                        \
        _Pragma("unroll")                                                      \
        for (int k = 0; k < 4; ++k) dst[tid + k * THR] = st[k];                \
        __syncthreads();                                                       \
        if ((S) + 1 < NS) {                                                    \
            const uint4* g = (const uint4*)((const char*)P2 + (size_t)((S) + 1) * SLICE); \
            _Pragma("unroll")                                                  \
            for (int k = 0; k < 4; ++k) st[k] = g[tid + k * THR];              \
        }                                                                      \
        const char* buf = s_P + ((S) & 1) * SLICE;                             \
        _Pragma("unroll")                                                      \
        for (int i = 0; i < 4; ++i) {                                          \
            int c = (int)s_cats[(r0 + i) * NT + (T)];                          \
            uint4 pa = *(const uint4*)(buf + c * 16);                          \
            uint4 pb = *(const uint4*)(buf + 16384 + c * 16);                  \
            UNP8(ACC, i, 0, pa)                                                \
            UNP8(ACC, i, 8, pb)                                                \
        }                                                                      \
    }

__global__ void __launch_bounds__(THR, 2)
fwd_lds(const int* __restrict__ xcat, const float* __restrict__ xcont,
        const unsigned short* __restrict__ P2,
        const float* __restrict__ W, const float* __restrict__ Wc,
        const float* __restrict__ bc, const float* __restrict__ bias,
        float* __restrict__ out, int nrows) {
    __shared__ unsigned short s_cats[RPB * NT];  // 86016 B
    __shared__ char s_P[2 * SLICE];              // 65536 B (double buffer)

    const int tid = threadIdx.x;
    const long rbase = (long)blockIdx.x * RPB;
    const long totalc = (long)nrows * NT;

    // ---- stage this block's categorical indices as u16 (coalesced) ----
    {
        const long base4 = rbase * NT / 4;       // RPB*NT divisible by 4
        const uint4* s4 = (const uint4*)xcat;
        #pragma unroll
        for (int it = 0; it < (RPB * NT / 4) / THR; ++it) {   // 21 iters
            int n = tid + it * THR;
            long e0 = (base4 + n) * 4;
            uint4 v = make_uint4(0u, 0u, 0u, 0u);
            if (e0 + 3 < totalc) {
                v = s4[base4 + n];
            } else {
                if (e0     < totalc) v.x = (unsigned)xcat[e0];
                if (e0 + 1 < totalc) v.y = (unsigned)xcat[e0 + 1];
                if (e0 + 2 < totalc) v.z = (unsigned)xcat[e0 + 2];
                if (e0 + 3 < totalc) v.w = (unsigned)xcat[e0 + 3];
            }
            u32x2 p;
            p.x = (v.x & 0xFFFFu) | (v.y << 16);
            p.y = (v.z & 0xFFFFu) | (v.w << 16);
            *(u32x2*)((char*)s_cats + (size_t)n * 8) = p;
        }
    }
    // (first use of s_cats is after stage 0's barrier)

    // ---- prefetch slice 0 into registers ----
    uint4 st[4];
    {
        const uint4* g = (const uint4*)P2;
        #pragma unroll
        for (int k = 0; k < 4; ++k) st[k] = g[tid + k * THR];
    }

    float accA[4][16], accB[4][16];
    #pragma unroll
    for (int i = 0; i < 4; ++i) {
        #pragma unroll
        for (int j = 0; j < 16; ++j) { accA[i][j] = 0.f; accB[i][j] = 0.f; }
    }

    const int r0 = tid * 4;   // 4 consecutive local rows per thread

    for (int s = 0;  s < NT; ++s) STAGE(s, s,      accA)
    for (int s = NT; s < NS; ++s) STAGE(s, s - NT, accB)

    // ---- epilogue: continuous branch + bias + lrelu + store ----
    const long grow = rbase + r0;
    if (grow >= nrows) return;

    float xc[4];
    if (grow + 3 < nrows) {
        f32x4 x4 = *(const f32x4*)(xcont + grow);
        xc[0] = x4.x; xc[1] = x4.y; xc[2] = x4.z; xc[3] = x4.w;
    } else {
        #pragma unroll
        for (int i = 0; i < 4; ++i)
            xc[i] = (grow + i < nrows) ? xcont[grow + i] : 0.f;
    }

    float cv[4][8];
    #pragma unroll
    for (int i = 0; i < 4; ++i) {
        #pragma unroll
        for (int k = 0; k < 8; ++k)
            cv[i][k] = lrelu(fmaf(xc[i], Wc[k], bc[k]));
    }

    #pragma unroll
    for (int i = 0; i < 4; ++i) {
        if (grow + i < nrows) {
            float* orow = out + (size_t)(grow + i) * OD;
            #pragma unroll
            for (int q = 0; q < 4; ++q) {          // j = 0..15 from accA
                f32x4 v;
                #pragma unroll
                for (int e = 0; e < 4; ++e) {
                    int j = q * 4 + e;
                    float a = accA[i][j] + bias[j];
                    #pragma unroll
                    for (int k = 0; k < 8; ++k)
                        a = fmaf(cv[i][k], W[(size_t)j * CD + (CD - 8) + k], a);
                    v[e] = lrelu(a);
                }
                *(f32x4*)(orow + q * 4) = v;
            }
            #pragma unroll
            for (int q = 4; q < 8; ++q) {          // j = 16..31 from accB
                f32x4 v;
                #pragma unroll
                for (int e = 0; e < 4; ++e) {
                    int j = q * 4 + e;
                    float a = accB[i][j - 16] + bias[j];
                    #pragma unroll
                    for (int k = 0; k < 8; ++k)
                        a = fmaf(cv[i][k], W[(size_t)j * CD + (CD - 8) + k], a);
                    v[e] = lrelu(a);
                }
                *(f32x4*)(orow + q * 4) = v;
            }
        }
    }
}

// ---------------- fallback path (proven R16 kernels) ----------------
__global__ void build_P_fb(const float* __restrict__ tables,
                           const float* __restrict__ W,
                           unsigned short* __restrict__ P,
                           float* __restrict__ wt) {
    int idx = blockIdx.x * 256 + threadIdx.x;
    if (idx < NT * NC * OD) {
        int j = idx & 31;
        int c = (idx >> 5) % NC;
        int t = idx / (NC * OD);
        const float* trow = tables + (size_t)(t * NC + c) * 16;
        const float* wrow = W + (size_t)j * CD + t * 16;
        float acc = 0.f;
        #pragma unroll
        for (int k = 0; k < 16; ++k) acc = fmaf(trow[k], wrow[k], acc);
        P[idx] = f32_to_bf16_rne(acc);
    }
    if (blockIdx.x == 0 && threadIdx.x < 8 * OD) {
        int k = threadIdx.x >> 5;
        int j = threadIdx.x & 31;
        wt[k * OD + j] = W[(size_t)j * CD + (CD - 8) + k];
    }
}

__global__ void __launch_bounds__(256)
fwd_fb(const int* __restrict__ xcat, const float* __restrict__ xcont,
       const unsigned short* __restrict__ P, const float* __restrict__ Wc,
       const float* __restrict__ bc, const float* __restrict__ bias,
       const float* __restrict__ wt, float* __restrict__ out, int nrows) {
    __shared__ int s_cats[32 * NT];
    const int tid = threadIdx.x;
    const long blk_cat_base = (long)blockIdx.x * (32 * NT);
    const long total_cats = (long)nrows * NT;
    #pragma unroll
    for (int i = 0; i < 3; ++i) {
        int li = tid + i * 256;
        if (li < 32 * NT) {
            long g = blk_cat_base + li;
            if (g < total_cats) s_cats[li] = xcat[g];
        }
    }
    __syncthreads();
    const int row_local = tid >> 3;
    const int l = tid & 7;
    const int row = blockIdx.x * 32 + row_local;
    if (row >= nrows) return;
    int offs[NT];
    #pragma unroll
    for (int t = 0; t < NT; ++t) {
        int c = s_cats[row_local * NT + t];
        offs[t] = (t * NC + c) * OD + l * 4;
    }
    ushort4 u[NT];
    #pragma unroll
    for (int t = 0; t < NT; ++t)
        u[t] = *reinterpret_cast<const ushort4*>(P + offs[t]);
    float acc[4];
    const float* bsrc = bias + l * 4;
    #pragma unroll
    for (int m = 0; m < 4; ++m) acc[m] = bsrc[m];
    #pragma unroll
    for (int t = 0; t < NT; ++t) {
        acc[0] += __uint_as_float((unsigned)u[t].x << 16);
        acc[1] += __uint_as_float((unsigned)u[t].y << 16);
        acc[2] += __uint_as_float((unsigned)u[t].z << 16);
        acc[3] += __uint_as_float((unsigned)u[t].w << 16);
    }
    float x = xcont[row];
    #pragma unroll
    for (int k = 0; k < 8; ++k) {
        float cvv = lrelu(fmaf(x, Wc[k], bc[k]));
        const float* w = wt + k * OD + l * 4;
        #pragma unroll
        for (int m = 0; m < 4; ++m) acc[m] = fmaf(cvv, w[m], acc[m]);
    }
    #pragma unroll
    for (int m = 0; m < 4; ++m) acc[m] = lrelu(acc[m]);
    f32x4 v = { acc[0], acc[1], acc[2], acc[3] };
    *reinterpret_cast<f32x4*>(out + (size_t)row * OD + l * 4) = v;
}

extern "C" void kernel_launch(void* const* d_in, const int* in_sizes, int n_in,
                              void* d_out, int out_size, void* d_ws, size_t ws_size,
                              hipStream_t stream) {
    const int*   xcat   = (const int*)d_in[0];
    const float* xcont  = (const float*)d_in[1];
    const float* tables = (const float*)d_in[2];
    const float* Wc     = (const float*)d_in[3];
    const float* bc     = (const float*)d_in[4];
    const float* W      = (const float*)d_in[5];
    const float* bias   = (const float*)d_in[6];
    float* out = (float*)d_out;

    int nrows = in_sizes[0] / NT;

    if (ws_size >= (size_t)NS * SLICE) {
        unsigned short* P2 = (unsigned short*)d_ws;
        build_P2<<<(NS * 16384 + 255) / 256, 256, 0, stream>>>(tables, W, P2);
        int nb = (nrows + RPB - 1) / RPB;
        fwd_lds<<<nb, THR, 0, stream>>>(xcat, xcont, P2, W, Wc, bc, bias, out, nrows);
    } else {
        unsigned short* P = (unsigned short*)d_ws;
        float* wt = (float*)((char*)d_ws + (size_t)NT * NC * OD * 2);
        build_P_fb<<<(NT * NC * OD + 255) / 256, 256, 0, stream>>>(tables, W, P, wt);
        int nb = (nrows + 31) / 32;
        fwd_fb<<<nb, 256, 0, stream>>>(xcat, xcont, P, Wc, bc, bias, wt, out, nrows);
    }
}

// Round 18
// 81.867 us; speedup vs baseline: 1.6737x; 1.6737x over previous
//
#include <hip/hip_runtime.h>
#include <hip/hip_bf16.h>

#define NUM_TABLES 21
#define NUM_CATS   1000
#define EMB_DIM    16
#define CONCAT_DIM 344
#define OUT_DIM    32
#define NEG_SLOPE  0.01f

#define ROWS_PER_BLOCK 32          // 256 threads, 8 lanes per row
#define CATS_PER_BLOCK (ROWS_PER_BLOCK * NUM_TABLES)  // 672 ints

typedef float f32x4 __attribute__((ext_vector_type(4)));

// ---------- helpers ----------
__device__ __forceinline__ unsigned short f32_to_bf16_rne(float f) {
    unsigned int u = __float_as_uint(f);
    unsigned int r = u + 0x7FFFu + ((u >> 16) & 1u);  // round to nearest even
    return (unsigned short)(r >> 16);
}
__device__ __forceinline__ float lrelu(float v) {
    return v >= 0.f ? v : NEG_SLOPE * v;
}

// ---------- kernel 1: precompute P[t][c][j] = tables[t,c,:] . W[j, 16t:16t+16] (bf16)
// One P row = 32 bf16 = 64 B = one cache line per (table, category).
// Also packs wt[k][j] = W[j][336+k] (f32) for coalesced loads in kernel 2.
__global__ void build_P(const float* __restrict__ tables,
                        const float* __restrict__ W,
                        unsigned short* __restrict__ P,
                        float* __restrict__ wt) {
    int idx = blockIdx.x * 256 + threadIdx.x;
    if (idx < NUM_TABLES * NUM_CATS * OUT_DIM) {
        int j = idx & 31;
        int c = (idx >> 5) % NUM_CATS;
        int t = idx / (NUM_CATS * OUT_DIM);
        const float* trow = tables + (size_t)(t * NUM_CATS + c) * EMB_DIM;
        const float* wrow = W + (size_t)j * CONCAT_DIM + t * EMB_DIM;
        float acc = 0.f;
        #pragma unroll
        for (int k = 0; k < EMB_DIM; ++k) acc = fmaf(trow[k], wrow[k], acc);
        P[idx] = f32_to_bf16_rne(acc);
    }
    if (blockIdx.x == 0 && threadIdx.x < 8 * OUT_DIM) {
        int k = threadIdx.x >> 5;
        int j = threadIdx.x & 31;
        wt[k * OUT_DIM + j] = W[(size_t)j * CONCAT_DIM + (CONCAT_DIM - 8) + k];
    }
}

// ---------- kernel 2 (R16 structure; single change: agent-scope P gathers) ----------
// 8 lanes per row; each lane owns 4 consecutive outputs. The 21 P gathers are
// relaxed AGENT-scope loads -> global_load_dwordx2 with sc1: bypass the CU L1
// (whose miss-path/MSHR equilibrium is the measured 77 us plateau) but stay
// cached in L2 (R14 proved L2-bypass `nt` is 2.2x worse). L2 has ~4x BW
// headroom at the current service rate.
__global__ void __launch_bounds__(256)
fwd(const int* __restrict__ xcat,
    const float* __restrict__ xcont,
    const unsigned short* __restrict__ P,
    const float* __restrict__ Wc,
    const float* __restrict__ bc,
    const float* __restrict__ bias,
    const float* __restrict__ wt,
    float* __restrict__ out,
    int nrows) {
    __shared__ int s_cats[CATS_PER_BLOCK];

    const int tid = threadIdx.x;
    const long blk_cat_base = (long)blockIdx.x * CATS_PER_BLOCK;
    const long total_cats = (long)nrows * NUM_TABLES;

    // coalesced stage of this block's 32 rows of categorical indices
    #pragma unroll
    for (int i = 0; i < 3; ++i) {
        int li = tid + i * 256;
        if (li < CATS_PER_BLOCK) {
            long g = blk_cat_base + li;
            if (g < total_cats) s_cats[li] = xcat[g];
        }
    }
    __syncthreads();

    const int row_local = tid >> 3;
    const int l = tid & 7;
    const int row = blockIdx.x * ROWS_PER_BLOCK + row_local;
    if (row >= nrows) return;

    // offsets (LDS broadcast reads)
    int offs[NUM_TABLES];
    #pragma unroll
    for (int t = 0; t < NUM_TABLES; ++t) {
        int c = s_cats[row_local * NUM_TABLES + t];
        offs[t] = (t * NUM_CATS + c) * OUT_DIM + l * 4;
    }

    // gathers: 8B agent-scope loads (sc1: L1-bypass, L2-served)
    unsigned long long u[NUM_TABLES];
    #pragma unroll
    for (int t = 0; t < NUM_TABLES; ++t)
        u[t] = __hip_atomic_load(
            reinterpret_cast<const unsigned long long*>(P + offs[t]),
            __ATOMIC_RELAXED, __HIP_MEMORY_SCOPE_AGENT);

    // accumulate: unpack 4 bf16 from each 8B word
    float acc[4];
    const float* bsrc = bias + l * 4;
    #pragma unroll
    for (int m = 0; m < 4; ++m) acc[m] = bsrc[m];

    #pragma unroll
    for (int t = 0; t < NUM_TABLES; ++t) {
        unsigned int lo = (unsigned int)u[t];
        unsigned int hi = (unsigned int)(u[t] >> 32);
        acc[0] += __uint_as_float(lo << 16);
        acc[1] += __uint_as_float(lo & 0xFFFF0000u);
        acc[2] += __uint_as_float(hi << 16);
        acc[3] += __uint_as_float(hi & 0xFFFF0000u);
    }

    // continuous branch
    float x = xcont[row];
    #pragma unroll
    for (int k = 0; k < 8; ++k) {
        float cv = lrelu(fmaf(x, Wc[k], bc[k]));
        const float* w = wt + k * OUT_DIM + l * 4;
        #pragma unroll
        for (int m = 0; m < 4; ++m)
            acc[m] = fmaf(cv, w[m], acc[m]);
    }

    #pragma unroll
    for (int m = 0; m < 4; ++m) acc[m] = lrelu(acc[m]);

    f32x4 v = { acc[0], acc[1], acc[2], acc[3] };
    *reinterpret_cast<f32x4*>(out + (size_t)row * OUT_DIM + l * 4) = v;
}

extern "C" void kernel_launch(void* const* d_in, const int* in_sizes, int n_in,
                              void* d_out, int out_size, void* d_ws, size_t ws_size,
                              hipStream_t stream) {
    const int*   xcat   = (const int*)d_in[0];
    const float* xcont  = (const float*)d_in[1];
    const float* tables = (const float*)d_in[2];
    const float* Wc     = (const float*)d_in[3];
    const float* bc     = (const float*)d_in[4];
    const float* W      = (const float*)d_in[5];
    const float* bias   = (const float*)d_in[6];
    float* out = (float*)d_out;

    int nrows = in_sizes[0] / NUM_TABLES;

    const size_t P_elems = (size_t)NUM_TABLES * NUM_CATS * OUT_DIM;  // 672000
    const size_t P_bytes = P_elems * sizeof(unsigned short);
    const size_t wt_off  = P_bytes;

    unsigned short* P = (unsigned short*)d_ws;
    float* wt = (float*)((char*)d_ws + wt_off);

    int blocks1 = (int)((P_elems + 255) / 256);
    build_P<<<blocks1, 256, 0, stream>>>(tables, W, P, wt);

    int blocks2 = (nrows + ROWS_PER_BLOCK - 1) / ROWS_PER_BLOCK;
    fwd<<<blocks2, 256, 0, stream>>>(xcat, xcont, P, Wc, bc, bias, wt, out, nrows);
}

// Round 19
// 77.420 us; speedup vs baseline: 1.7699x; 1.0574x over previous
//
#include <hip/hip_runtime.h>
#include <hip/hip_bf16.h>

#define NUM_TABLES 21
#define NUM_CATS   1000
#define EMB_DIM    16
#define CONCAT_DIM 344
#define OUT_DIM    32
#define NEG_SLOPE  0.01f

#define ROWS_PER_BLOCK 32          // 256 threads, 8 lanes per row
#define CATS_PER_BLOCK (ROWS_PER_BLOCK * NUM_TABLES)  // 672 ints

typedef float f32x4 __attribute__((ext_vector_type(4)));

// ---------- helpers ----------
__device__ __forceinline__ unsigned short f32_to_bf16_rne(float f) {
    unsigned int u = __float_as_uint(f);
    unsigned int r = u + 0x7FFFu + ((u >> 16) & 1u);  // round to nearest even
    return (unsigned short)(r >> 16);
}
__device__ __forceinline__ float bf16_to_f32(unsigned short h) {
    return __uint_as_float(((unsigned int)h) << 16);
}
__device__ __forceinline__ float lrelu(float v) {
    return v >= 0.f ? v : NEG_SLOPE * v;
}

// ---------- kernel 1: precompute P[t][c][j] = tables[t,c,:] . W[j, 16t:16t+16] (bf16)
// One P row = 32 bf16 = 64 B = exactly one cache line per (table, category).
// Also packs wt[k][j] = W[j][336+k] (f32) for coalesced loads in kernel 2.
__global__ void build_P(const float* __restrict__ tables,
                        const float* __restrict__ W,
                        unsigned short* __restrict__ P,
                        float* __restrict__ wt) {
    int idx = blockIdx.x * 256 + threadIdx.x;
    if (idx < NUM_TABLES * NUM_CATS * OUT_DIM) {
        int j = idx & 31;
        int c = (idx >> 5) % NUM_CATS;
        int t = idx / (NUM_CATS * OUT_DIM);
        const float* trow = tables + (size_t)(t * NUM_CATS + c) * EMB_DIM;
        const float* wrow = W + (size_t)j * CONCAT_DIM + t * EMB_DIM;
        float acc = 0.f;
        #pragma unroll
        for (int k = 0; k < EMB_DIM; ++k) acc = fmaf(trow[k], wrow[k], acc);
        P[idx] = f32_to_bf16_rne(acc);
    }
    if (blockIdx.x == 0 && threadIdx.x < 8 * OUT_DIM) {
        int k = threadIdx.x >> 5;
        int j = threadIdx.x & 31;
        wt[k * OUT_DIM + j] = W[(size_t)j * CONCAT_DIM + (CONCAT_DIM - 8) + k];
    }
}

// ---------- kernel 2 (final: R7/R16 structure, plain loads everywhere) ----------
// 8 lanes per row; each lane owns 4 consecutive outputs. x_cat staged through
// LDS (coalesced). The 21 P gathers are the kernel: 10.5M independent random
// 64B line-fetches served at the per-CU outstanding-request x L2-latency
// equilibrium (~4.6 cyc/line/CU) — the measured structural floor for this op
// (9 variants bracket 74-95 us; L2-bypass 2.2x worse, LDS-gather 1.8x worse,
// L1-bypass flat).
__global__ void __launch_bounds__(256)
fwd(const int* __restrict__ xcat,
    const float* __restrict__ xcont,
    const unsigned short* __restrict__ P,
    const float* __restrict__ Wc,
    const float* __restrict__ bc,
    const float* __restrict__ bias,
    const float* __restrict__ wt,
    float* __restrict__ out,
    int nrows) {
    __shared__ int s_cats[CATS_PER_BLOCK];

    const int tid = threadIdx.x;
    const long blk_cat_base = (long)blockIdx.x * CATS_PER_BLOCK;
    const long total_cats = (long)nrows * NUM_TABLES;

    // coalesced stage of this block's 32 rows of categorical indices
    #pragma unroll
    for (int i = 0; i < 3; ++i) {
        int li = tid + i * 256;
        if (li < CATS_PER_BLOCK) {
            long g = blk_cat_base + li;
            if (g < total_cats) s_cats[li] = xcat[g];
        }
    }
    __syncthreads();

    const int row_local = tid >> 3;
    const int l = tid & 7;
    const int row = blockIdx.x * ROWS_PER_BLOCK + row_local;
    if (row >= nrows) return;

    // offsets (LDS broadcast reads)
    int offs[NUM_TABLES];
    #pragma unroll
    for (int t = 0; t < NUM_TABLES; ++t) {
        int c = s_cats[row_local * NUM_TABLES + t];
        offs[t] = (t * NUM_CATS + c) * OUT_DIM + l * 4;
    }

    // gathers: plain 8B loads (L2-served)
    ushort4 u[NUM_TABLES];
    #pragma unroll
    for (int t = 0; t < NUM_TABLES; ++t)
        u[t] = *reinterpret_cast<const ushort4*>(P + offs[t]);

    // accumulate
    float acc[4];
    const float* bsrc = bias + l * 4;
    #pragma unroll
    for (int m = 0; m < 4; ++m) acc[m] = bsrc[m];

    #pragma unroll
    for (int t = 0; t < NUM_TABLES; ++t) {
        acc[0] += bf16_to_f32(u[t].x);
        acc[1] += bf16_to_f32(u[t].y);
        acc[2] += bf16_to_f32(u[t].z);
        acc[3] += bf16_to_f32(u[t].w);
    }

    // continuous branch
    float x = xcont[row];
    #pragma unroll
    for (int k = 0; k < 8; ++k) {
        float cv = lrelu(fmaf(x, Wc[k], bc[k]));
        const float* w = wt + k * OUT_DIM + l * 4;
        #pragma unroll
        for (int m = 0; m < 4; ++m)
            acc[m] = fmaf(cv, w[m], acc[m]);
    }

    #pragma unroll
    for (int m = 0; m < 4; ++m) acc[m] = lrelu(acc[m]);

    f32x4 v = { acc[0], acc[1], acc[2], acc[3] };
    *reinterpret_cast<f32x4*>(out + (size_t)row * OUT_DIM + l * 4) = v;
}

extern "C" void kernel_launch(void* const* d_in, const int* in_sizes, int n_in,
                              void* d_out, int out_size, void* d_ws, size_t ws_size,
                              hipStream_t stream) {
    const int*   xcat   = (const int*)d_in[0];
    const float* xcont  = (const float*)d_in[1];
    const float* tables = (const float*)d_in[2];
    const float* Wc     = (const float*)d_in[3];
    const float* bc     = (const float*)d_in[4];
    const float* W      = (const float*)d_in[5];
    const float* bias   = (const float*)d_in[6];
    float* out = (float*)d_out;

    int nrows = in_sizes[0] / NUM_TABLES;

    const size_t P_elems = (size_t)NUM_TABLES * NUM_CATS * OUT_DIM;  // 672000
    const size_t P_bytes = P_elems * sizeof(unsigned short);
    const size_t wt_off  = P_bytes;

    unsigned short* P = (unsigned short*)d_ws;
    float* wt = (float*)((char*)d_ws + wt_off);

    int blocks1 = (int)((P_elems + 255) / 256);
    build_P<<<blocks1, 256, 0, stream>>>(tables, W, P, wt);

    int blocks2 = (nrows + ROWS_PER_BLOCK - 1) / ROWS_PER_BLOCK;
    fwd<<<blocks2, 256, 0, stream>>>(xcat, xcont, P, Wc, bc, bias, wt, out, nrows);
}